// Round 4
// baseline (3713.787 us; speedup 1.0000x reference)
//
#include <hip/hip_runtime.h>
#include <hip/hip_bf16.h>

#define N 4096
#define D 512
#define NBLK 256
#define LOG2E 1.4426950408889634f
#define LN2   0.6931471805599453f
#define LA2   (-12.0f)                 // -log2(4096) = la * log2e
#define VADD  15.635532333438686f      // -(la + lb + 1), exact objective constant

typedef unsigned short u16;
typedef __attribute__((ext_vector_type(8))) short short8;
typedef __attribute__((ext_vector_type(8))) unsigned short ushort8;
typedef __attribute__((ext_vector_type(4))) float fvec4;

struct __align__(128) Line { float v[16]; unsigned tag; unsigned pad[15]; };

static __device__ __forceinline__ unsigned short f2bf(float x) {
    __hip_bfloat16 h = __float2bfloat16(x);  // RNE
    unsigned short u;
    __builtin_memcpy(&u, &h, 2);
    return u;
}

static __device__ __forceinline__ void gld_lds16(const u16* gp, u16* lp) {
    __builtin_amdgcn_global_load_lds(
        (__attribute__((address_space(1))) void*)(u16*)gp,
        (__attribute__((address_space(3))) void*)lp, 16, 0, 0);
}

// exp2 / log2 / max3 as single HW ops
static __device__ __forceinline__ float ex2(float x) {
    float r; asm("v_exp_f32 %0, %1" : "=v"(r) : "v"(x)); return r;
}
static __device__ __forceinline__ float lg2(float x) {
    float r; asm("v_log_f32 %0, %1" : "=v"(r) : "v"(x)); return r;
}
static __device__ __forceinline__ float max3f(float a, float b, float c) {
    float r; asm("v_max3_f32 %0, %1, %2, %3" : "=v"(r) : "v"(a), "v"(b), "v"(c)); return r;
}

static __device__ __forceinline__ float agload(const float* p) {
    return __hip_atomic_load(p, __ATOMIC_RELAXED, __HIP_MEMORY_SCOPE_AGENT);
}
static __device__ __forceinline__ unsigned long long agload64(const unsigned long long* p) {
    return __hip_atomic_load(p, __ATOMIC_RELAXED, __HIP_MEMORY_SCOPE_AGENT);
}
static __device__ __forceinline__ void agstore(float* p, float v) {
    __hip_atomic_store(p, v, __ATOMIC_RELAXED, __HIP_MEMORY_SCOPE_AGENT);
}
static __device__ __forceinline__ unsigned tagload(const unsigned* p) {
    return __hip_atomic_load(p, __ATOMIC_RELAXED, __HIP_MEMORY_SCOPE_AGENT);
}
static __device__ __forceinline__ void tagstore(unsigned* p, unsigned v) {
    __hip_atomic_store(p, v, __ATOMIC_RELAXED, __HIP_MEMORY_SCOPE_AGENT);
}

// ---------------- fp32 -> bf16 convert (8 elems/thread) ----------------
__global__ __launch_bounds__(256) void f32_to_bf16_k(const float* __restrict__ in,
                                                     u16* __restrict__ out) {
    int idx = blockIdx.x * 256 + threadIdx.x;
    fvec4 a = *((const fvec4*)in + idx * 2);
    fvec4 b = *((const fvec4*)in + idx * 2 + 1);
    ushort8 o;
#pragma unroll
    for (int e = 0; e < 4; ++e) { o[e] = f2bf(a[e]); o[4 + e] = f2bf(b[e]); }
    *((ushort8*)out + idx) = o;
}

// ---------------- row squared-norms: one wave per row ----------------
__global__ __launch_bounds__(256) void row_norms_k(const float* __restrict__ X,
                                                   float* __restrict__ out) {
    int wave = threadIdx.x >> 6;
    int lane = threadIdx.x & 63;
    int row  = blockIdx.x * 4 + wave;
    const float* xr = X + (size_t)row * D;
    float s = 0.f;
#pragma unroll
    for (int k = 0; k < D / 64; ++k) {
        float v = xr[lane + 64 * k];
        s += v * v;
    }
#pragma unroll
    for (int off = 32; off >= 1; off >>= 1) s += __shfl_down(s, off);
    if (lane == 0) out[row] = s;
}

// ---------------- cost matrix via bf16 MFMA; stores M*log2e -----------
__global__ __launch_bounds__(256) void gemm_cost_bf16_k(const u16* __restrict__ A,
                                                        const u16* __restrict__ B,
                                                        const float* __restrict__ x2,
                                                        const float* __restrict__ y2,
                                                        u16* __restrict__ M) {
    __shared__ u16 As[128 * 32];
    __shared__ u16 Bs[128 * 32];
    int tid = threadIdx.x;
    int wave = tid >> 6, lane = tid & 63;
    int i0 = blockIdx.y * 128, j0 = blockIdx.x * 128;
    int wr = (wave >> 1) * 64, wc = (wave & 1) * 64;

    fvec4 acc[4][4] = {};

    int srow = wave * 16 + (lane >> 2);
    int skk  = (lane & 3) * 8;
    const u16* ga0 = A + (size_t)(i0 + srow) * D + skk;
    const u16* ga1 = A + (size_t)(i0 + 64 + srow) * D + skk;
    const u16* gb0 = B + (size_t)(j0 + srow) * D + skk;
    const u16* gb1 = B + (size_t)(j0 + 64 + srow) * D + skk;
    u16* la0 = &As[(wave * 16) * 32];
    u16* la1 = &As[(64 + wave * 16) * 32];
    u16* lb0 = &Bs[(wave * 16) * 32];
    u16* lb1 = &Bs[(64 + wave * 16) * 32];

    int fr = lane & 15, q = lane >> 4;

    for (int k0 = 0; k0 < D; k0 += 32) {
        __syncthreads();
        gld_lds16(ga0 + k0, la0);
        gld_lds16(ga1 + k0, la1);
        gld_lds16(gb0 + k0, lb0);
        gld_lds16(gb1 + k0, lb1);
        __syncthreads();
        short8 af[4], bf[4];
#pragma unroll
        for (int t = 0; t < 4; ++t) {
            af[t] = *(const short8*)&As[(wr + t * 16 + fr) * 32 + q * 8];
            bf[t] = *(const short8*)&Bs[(wc + t * 16 + fr) * 32 + q * 8];
        }
#pragma unroll
        for (int ri = 0; ri < 4; ++ri)
#pragma unroll
            for (int ci = 0; ci < 4; ++ci)
                acc[ri][ci] = __builtin_amdgcn_mfma_f32_16x16x32_bf16(af[ri], bf[ci],
                                                                      acc[ri][ci], 0, 0, 0);
    }

#pragma unroll
    for (int ri = 0; ri < 4; ++ri) {
#pragma unroll
        for (int ci = 0; ci < 4; ++ci) {
            int j = j0 + wc + ci * 16 + fr;
            float yj = y2[j];
#pragma unroll
            for (int r = 0; r < 4; ++r) {
                int i = i0 + wr + ri * 16 + q * 4 + r;
                float val = fmaxf(x2[i] + yj - 2.0f * acc[ri][ci][r], 0.0f) * LOG2E;
                M[(size_t)i * N + j] = f2bf(val);
            }
        }
    }
}

// ---------------- bf16 LDS-tiled transpose ----------------
__global__ __launch_bounds__(256) void transpose_bf16_k(const u16* __restrict__ in,
                                                        u16* __restrict__ out) {
    __shared__ u16 tile[64][66];
    int bx = blockIdx.x * 64, by = blockIdx.y * 64;
    int tx = threadIdx.x & 63, ty = threadIdx.x >> 6;
#pragma unroll
    for (int r = 0; r < 64; r += 4)
        tile[r + ty][tx] = in[(size_t)(by + r + ty) * N + bx + tx];
    __syncthreads();
#pragma unroll
    for (int r = 0; r < 64; r += 4)
        out[(size_t)(bx + r + ty) * N + by + tx] = tile[tx][r + ty];
}

// =====================================================================
// Persistent Sinkhorn v3: dataflow sync (no grid barrier, no counters).
// 256 blocks x 1024 threads. Block b publishes its 16 results into
// Line[b] = [16 floats][tag]; tag written after vmcnt(0) (completion-
// ordered at coherence point). Readers poll tags only, then load values.
// exp2-domain throughout (M pre-scaled by log2e). M rows prefetched to
// VGPRs before the poll to hide L3 latency.
// =====================================================================

static __device__ __forceinline__ int swz(int k) { return k ^ ((k >> 3) & 1); }

static __device__ __forceinline__ void prefM(const u16* __restrict__ row, ushort8* mreg) {
    int lane = threadIdx.x & 63;
#pragma unroll
    for (int c = 0; c < 8; ++c)
        mreg[c] = *(const ushort8*)(row + c * 512 + lane * 8);
}

// poll tags (1 poller per line), then stage all 4096 floats into LDS.
static __device__ __forceinline__ void poll_and_stage(Line* __restrict__ Ls, unsigned need,
                                                      float* __restrict__ vlds) {
    int t = threadIdx.x;
    if ((t & 3) == 0) {
        const unsigned* tp = &Ls[t >> 2].tag;
        while (tagload(tp) < need) __builtin_amdgcn_s_sleep(1);
    }
    __syncthreads();
    const unsigned long long* p =
        (const unsigned long long*)&Ls[t >> 2].v[(t & 3) * 4];
    unsigned long long a = agload64(p);
    unsigned long long b = agload64(p + 1);
    fvec4 vv;
    vv[0] = __uint_as_float((unsigned)a);
    vv[1] = __uint_as_float((unsigned)(a >> 32));
    vv[2] = __uint_as_float((unsigned)b);
    vv[3] = __uint_as_float((unsigned)(b >> 32));
    *(fvec4*)&vlds[swz(t) << 2] = vv;  // float-group t
}

// wave0 publishes 16 gathered values + tag (completion-ordered).
static __device__ __forceinline__ void publish(Line* __restrict__ L,
                                               const float* __restrict__ ps, unsigned tag) {
    int t = threadIdx.x;
    if (t < 16) agstore(&L->v[t], ps[t]);
    if (t < 64) {
        asm volatile("s_waitcnt vmcnt(0)" ::: "memory");
        if (t == 0) tagstore(&L->tag, tag);
    }
}

// LSE over one row (exp2 domain): returns LA2 - (m + log2(s)), all lanes.
static __device__ __forceinline__ float lse_half(const ushort8* mreg,
                                                 const float* __restrict__ lds) {
    int lane = threadIdx.x & 63;
    float m = -1e30f, s = 0.f;
#pragma unroll
    for (int c = 0; c < 8; ++c) {
        int k0 = c * 128 + lane * 2;
        fvec4 g0 = *(const fvec4*)&lds[swz(k0) << 2];
        fvec4 g1 = *(const fvec4*)&lds[swz(k0 + 1) << 2];
        const unsigned* mu = (const unsigned*)&mreg[c];
        float tv[8];
#pragma unroll
        for (int k = 0; k < 4; ++k) {
            unsigned u = mu[k];
            float flo = __uint_as_float(u << 16);
            float fhi = __uint_as_float(u & 0xffff0000u);
            float ga = (k < 2) ? g0[2 * k] : g1[2 * k - 4];
            float gb = (k < 2) ? g0[2 * k + 1] : g1[2 * k - 3];
            tv[2 * k]     = ga - flo;
            tv[2 * k + 1] = gb - fhi;
        }
        // chunk max folded with running max: mh >= m always
        float mh = fmaxf(fmaxf(max3f(tv[0], tv[1], tv[2]), max3f(tv[3], tv[4], tv[5])),
                         max3f(tv[6], tv[7], m));
        float sh = 0.f;
#pragma unroll
        for (int e = 0; e < 8; ++e) sh += ex2(tv[e] - mh);
        s = fmaf(s, ex2(m - mh), sh);
        m = mh;
    }
#pragma unroll
    for (int off = 32; off >= 1; off >>= 1) {
        float mo = __shfl_xor(m, off);
        float so = __shfl_xor(s, off);
        float mn = fmaxf(m, mo);
        s = fmaf(s, ex2(m - mn), so * ex2(mo - mn));
        m = mn;
    }
    return LA2 - (m + lg2(s));
}

// objective partial (exp2 domain): sum p*(ln2*(f2+g2) + VADD), all lanes.
static __device__ __forceinline__ float value_body(const ushort8* mreg,
                                                   const float* __restrict__ lds, float f2) {
    int lane = threadIdx.x & 63;
    float local = 0.f;
#pragma unroll
    for (int c = 0; c < 8; ++c) {
        int k0 = c * 128 + lane * 2;
        fvec4 g0 = *(const fvec4*)&lds[swz(k0) << 2];
        fvec4 g1 = *(const fvec4*)&lds[swz(k0 + 1) << 2];
        const unsigned* mu = (const unsigned*)&mreg[c];
#pragma unroll
        for (int k = 0; k < 4; ++k) {
            unsigned u = mu[k];
            float mv0 = __uint_as_float(u << 16);
            float mv1 = __uint_as_float(u & 0xffff0000u);
            float ga = (k < 2) ? g0[2 * k] : g1[2 * k - 4];
            float gb = (k < 2) ? g0[2 * k + 1] : g1[2 * k - 3];
            float a0 = f2 + ga, a1 = f2 + gb;
            local = fmaf(ex2(a0 - mv0), fmaf(LN2, a0, VADD), local);
            local = fmaf(ex2(a1 - mv1), fmaf(LN2, a1, VADD), local);
        }
    }
#pragma unroll
    for (int off = 32; off >= 1; off >>= 1) local += __shfl_xor(local, off);
    return local;
}

__global__ __launch_bounds__(1024, 4) void sinkhorn_persist3_k(
        const u16* __restrict__ Mb, const u16* __restrict__ MTb,
        Line* fl, Line* gl, Line* pl, float* __restrict__ out) {
    __shared__ float vlds[4096];
    __shared__ float ps[16];
    __shared__ float fs[16];
    int t = threadIdx.x;
    int b = blockIdx.x;
    int wave = t >> 6, lane = t & 63;
    int wid = (b << 4) | wave;
    const u16* rowM  = Mb  + ((size_t)wid << 12);
    const u16* rowMT = MTb + ((size_t)wid << 12);
    ushort8 mreg[8];
    float flast = 0.f;

    for (int it = 0; it < 100; ++it) {
        // ---- f-half: f = LA2 - LSE(g - M) ----
        prefM(rowM, mreg);
        poll_and_stage(gl, (unsigned)it, vlds);  // it=0: memset zeros = g0
        __syncthreads();
        float f2v = lse_half(mreg, vlds);
        flast = f2v;
        if (lane == 0) ps[wave] = f2v;
        __syncthreads();
        publish(&fl[b], ps, (unsigned)(it + 1));
        // ---- g-half: g = LA2 - LSE(f - M^T) ----
        prefM(rowMT, mreg);
        poll_and_stage(fl, (unsigned)(it + 1), vlds);
        __syncthreads();
        float g2v = lse_half(mreg, vlds);
        if (lane == 0) ps[wave] = g2v;
        __syncthreads();
        publish(&gl[b], ps, (unsigned)(it + 1));
    }

    // ---- value phase ----
    prefM(rowM, mreg);
    poll_and_stage(gl, 100u, vlds);
    __syncthreads();
    float loc = value_body(mreg, vlds, flast);
    if (lane == 0) ps[wave] = loc;
    __syncthreads();
    if (t == 0) {
        float bsum = 0.f;
#pragma unroll
        for (int w = 0; w < 16; ++w) bsum += ps[w];
        agstore(&pl[b].v[0], bsum);
        asm volatile("s_waitcnt vmcnt(0)" ::: "memory");
        tagstore(&pl[b].tag, 1u);
    }
    if (b == 0) {
        float x = 0.f;
        if (t < NBLK) {
            const unsigned* tp = &pl[t].tag;
            while (tagload(tp) < 1u) __builtin_amdgcn_s_sleep(1);
            x = agload(&pl[t].v[0]);
        }
#pragma unroll
        for (int off = 32; off >= 1; off >>= 1) x += __shfl_xor(x, off);
        if (lane == 0) fs[wave] = x;
        __syncthreads();
        if (t == 0) {
            float tot = 1.0f;
#pragma unroll
            for (int w = 0; w < 16; ++w) tot += fs[w];
            agstore(out, tot);
        }
    }
}

// ---------------- fallback path (multi-launch, exp2 domain) ----------------
__global__ __launch_bounds__(256, 4) void sinkhorn_half_w_k(const u16* __restrict__ Mr,
                                                            const float* __restrict__ vin,
                                                            float* __restrict__ vout) {
    int wid  = (blockIdx.x << 2) | (threadIdx.x >> 6);
    int lane = threadIdx.x & 63;
    const u16* row = Mr + ((size_t)wid << 12);
    float m = -1e30f, s = 0.f;
#pragma unroll
    for (int c = 0; c < 8; ++c) {
        int j = c * 512 + lane * 8;
        ushort8 m8 = *(const ushort8*)(row + j);
        fvec4 g0 = *(const fvec4*)(vin + j);
        fvec4 g1 = *(const fvec4*)(vin + j + 4);
        const unsigned* mu = (const unsigned*)&m8;
        float tv[8];
#pragma unroll
        for (int k = 0; k < 4; ++k) {
            unsigned u = mu[k];
            float flo = __uint_as_float(u << 16);
            float fhi = __uint_as_float(u & 0xffff0000u);
            float ga = (k < 2) ? g0[2 * k] : g1[2 * k - 4];
            float gb = (k < 2) ? g0[2 * k + 1] : g1[2 * k - 3];
            tv[2 * k]     = ga - flo;
            tv[2 * k + 1] = gb - fhi;
        }
        float mh = fmaxf(fmaxf(max3f(tv[0], tv[1], tv[2]), max3f(tv[3], tv[4], tv[5])),
                         max3f(tv[6], tv[7], m));
        float sh = 0.f;
#pragma unroll
        for (int e = 0; e < 8; ++e) sh += ex2(tv[e] - mh);
        s = fmaf(s, ex2(m - mh), sh);
        m = mh;
    }
#pragma unroll
    for (int off = 32; off >= 1; off >>= 1) {
        float mo = __shfl_xor(m, off);
        float so = __shfl_xor(s, off);
        float mn = fmaxf(m, mo);
        s = fmaf(s, ex2(m - mn), so * ex2(mo - mn));
        m = mn;
    }
    if (lane == 0) vout[wid] = LA2 - (m + lg2(s));
}

__global__ __launch_bounds__(256, 4) void ot_value_w_k(const u16* __restrict__ M,
                                                       const float* __restrict__ f,
                                                       const float* __restrict__ g,
                                                       float* __restrict__ partial) {
    int wid  = (blockIdx.x << 2) | (threadIdx.x >> 6);
    int lane = threadIdx.x & 63;
    const u16* row = M + ((size_t)wid << 12);
    float fi = f[wid];
    float local = 0.f;
#pragma unroll
    for (int c = 0; c < 8; ++c) {
        int j = c * 512 + lane * 8;
        ushort8 m8 = *(const ushort8*)(row + j);
        fvec4 g0 = *(const fvec4*)(g + j);
        fvec4 g1 = *(const fvec4*)(g + j + 4);
        const unsigned* mu = (const unsigned*)&m8;
#pragma unroll
        for (int k = 0; k < 4; ++k) {
            unsigned u = mu[k];
            float mv0 = __uint_as_float(u << 16);
            float mv1 = __uint_as_float(u & 0xffff0000u);
            float ga = (k < 2) ? g0[2 * k] : g1[2 * k - 4];
            float gb = (k < 2) ? g0[2 * k + 1] : g1[2 * k - 3];
            float a0 = fi + ga, a1 = fi + gb;
            local = fmaf(ex2(a0 - mv0), fmaf(LN2, a0, VADD), local);
            local = fmaf(ex2(a1 - mv1), fmaf(LN2, a1, VADD), local);
        }
    }
#pragma unroll
    for (int off = 32; off >= 1; off >>= 1) local += __shfl_xor(local, off);
    __shared__ float ps[4];
    if (lane == 0) ps[threadIdx.x >> 6] = local;
    __syncthreads();
    if (threadIdx.x == 0) partial[blockIdx.x] = ps[0] + ps[1] + ps[2] + ps[3];
}

__global__ __launch_bounds__(256) void value_reduce_k(const float* __restrict__ partial,
                                                      float* __restrict__ out) {
    int t = threadIdx.x;
    float s = partial[t] + partial[t + 256] + partial[t + 512] + partial[t + 768];
#pragma unroll
    for (int off = 32; off >= 1; off >>= 1) s += __shfl_xor(s, off);
    __shared__ float fs[4];
    if ((t & 63) == 0) fs[t >> 6] = s;
    __syncthreads();
    if (t == 0) out[0] = fs[0] + fs[1] + fs[2] + fs[3] + 1.0f;
}

extern "C" void kernel_launch(void* const* d_in, const int* in_sizes, int n_in,
                              void* d_out, int out_size, void* d_ws, size_t ws_size,
                              hipStream_t stream) {
    const float* src = (const float*)d_in[0];
    const float* tgt = (const float*)d_in[1];
    float* out = (float*)d_out;

    // workspace: Mb (32MB) | MTb (32MB) | Xb (4MB) | Yb (4MB) | x2 | y2 | f | g
    // dataflow lines + fallback partials alias Xb (dead after the GEMM).
    u16* Mb  = (u16*)d_ws;
    u16* MTb = Mb + (size_t)N * N;
    u16* Xb  = MTb + (size_t)N * N;
    u16* Yb  = Xb + (size_t)N * D;
    float* x2 = (float*)(Yb + (size_t)N * D);
    float* y2 = x2 + N;
    float* f  = y2 + N;
    float* g  = f + N;

    Line* fl = (Line*)Xb;        // 32 KB
    Line* gl = fl + NBLK;        // 32 KB
    Line* pl = gl + NBLK;        // 32 KB
    float* partial = (float*)(pl + NBLK);  // fallback partials (4 KB)

    hipMemsetAsync(f, 0, 2 * N * sizeof(float), stream);  // f,g contiguous (fallback)

    f32_to_bf16_k<<<N * D / (256 * 8), 256, 0, stream>>>(src, Xb);
    f32_to_bf16_k<<<N * D / (256 * 8), 256, 0, stream>>>(tgt, Yb);
    row_norms_k<<<N / 4, 256, 0, stream>>>(src, x2);
    row_norms_k<<<N / 4, 256, 0, stream>>>(tgt, y2);
    gemm_cost_bf16_k<<<dim3(N / 128, N / 128), 256, 0, stream>>>(Xb, Yb, x2, y2, Mb);
    transpose_bf16_k<<<dim3(N / 64, N / 64), 256, 0, stream>>>(Mb, MTb);

    // reset dataflow lines (after GEMM consumed Xb); zero tags + zero g0 values
    hipMemsetAsync(fl, 0, 3 * NBLK * sizeof(Line), stream);

    void* kargs[] = {(void*)&Mb, (void*)&MTb, (void*)&fl, (void*)&gl,
                     (void*)&pl, (void*)&out};
    hipError_t cerr = hipLaunchCooperativeKernel((const void*)sinkhorn_persist3_k,
                                                 dim3(NBLK), dim3(1024), kargs, 0, stream);
    if (cerr != hipSuccess) {
        // fallback: multi-launch path (exp2 domain)
        for (int it = 0; it < 100; ++it) {
            sinkhorn_half_w_k<<<N / 4, 256, 0, stream>>>(Mb,  g, f);
            sinkhorn_half_w_k<<<N / 4, 256, 0, stream>>>(MTb, f, g);
        }
        ot_value_w_k<<<N / 4, 256, 0, stream>>>(Mb, f, g, partial);
        value_reduce_k<<<1, 256, 0, stream>>>(partial, out);
    }
}

// Round 5
// 1311.375 us; speedup vs baseline: 2.8320x; 2.8320x over previous
//
#include <hip/hip_runtime.h>
#include <hip/hip_bf16.h>

#define N 4096
#define D 512
#define LOG2E 1.4426950408889634f
#define LN2   0.6931471805599453f
#define LA2   (-12.0f)                 // -log2(4096)
#define VADD  15.635532333438686f      // -(la + lb + 1)

typedef unsigned short u16;
typedef unsigned char u8;
typedef __attribute__((ext_vector_type(8))) short short8;
typedef __attribute__((ext_vector_type(8))) unsigned short ushort8;
typedef __attribute__((ext_vector_type(4))) float fvec4;
typedef __attribute__((ext_vector_type(2))) unsigned int uivec2;
typedef __attribute__((ext_vector_type(4))) unsigned int uivec4;

static __device__ __forceinline__ float bf2f(unsigned short u) {
    union { unsigned int i; float f; } c;
    c.i = ((unsigned int)u) << 16;
    return c.f;
}

static __device__ __forceinline__ unsigned short f2bf(float x) {
    __hip_bfloat16 h = __float2bfloat16(x);  // RNE
    unsigned short u;
    __builtin_memcpy(&u, &h, 2);
    return u;
}

static __device__ __forceinline__ void gld_lds16(const u16* gp, u16* lp) {
    __builtin_amdgcn_global_load_lds(
        (__attribute__((address_space(1))) void*)(u16*)gp,
        (__attribute__((address_space(3))) void*)lp, 16, 0, 0);
}

static __device__ __forceinline__ float ex2(float x) {
    float r; asm("v_exp_f32 %0, %1" : "=v"(r) : "v"(x)); return r;
}
static __device__ __forceinline__ float lg2(float x) {
    float r; asm("v_log_f32 %0, %1" : "=v"(r) : "v"(x)); return r;
}
static __device__ __forceinline__ float max3f(float a, float b, float c) {
    float r; asm("v_max3_f32 %0, %1, %2, %3" : "=v"(r) : "v"(a), "v"(b), "v"(c)); return r;
}

// ---------------- fp32 -> bf16 convert (8 elems/thread) ----------------
__global__ __launch_bounds__(256) void f32_to_bf16_k(const float* __restrict__ in,
                                                     u16* __restrict__ out) {
    int idx = blockIdx.x * 256 + threadIdx.x;
    fvec4 a = *((const fvec4*)in + idx * 2);
    fvec4 b = *((const fvec4*)in + idx * 2 + 1);
    ushort8 o;
#pragma unroll
    for (int e = 0; e < 4; ++e) { o[e] = f2bf(a[e]); o[4 + e] = f2bf(b[e]); }
    *((ushort8*)out + idx) = o;
}

// ---------------- row squared-norms * log2e ----------------
__global__ __launch_bounds__(256) void row_norms_k(const float* __restrict__ X,
                                                   float* __restrict__ out) {
    int wave = threadIdx.x >> 6;
    int lane = threadIdx.x & 63;
    int row  = blockIdx.x * 4 + wave;
    const float* xr = X + (size_t)row * D;
    float s = 0.f;
#pragma unroll
    for (int k = 0; k < D / 64; ++k) {
        float v = xr[lane + 64 * k];
        s += v * v;
    }
#pragma unroll
    for (int off = 32; off >= 1; off >>= 1) s += __shfl_down(s, off);
    if (lane == 0) out[row] = s * LOG2E;
}

// ---------------- dot-product matrix via bf16 MFMA (m97 pattern) -------
// DOT[i][j] = bf16(X_i . Y_j); also per-block max|dot| -> blockmax[]
__global__ __launch_bounds__(256) void gemm_dot_k(const u16* __restrict__ A,
                                                  const u16* __restrict__ B,
                                                  u16* __restrict__ DOT,
                                                  float* __restrict__ blockmax) {
    __shared__ u16 As[128 * 32];
    __shared__ u16 Bs[128 * 32];
    int tid = threadIdx.x;
    int wave = tid >> 6, lane = tid & 63;
    int i0 = blockIdx.y * 128, j0 = blockIdx.x * 128;
    int wr = (wave >> 1) * 64, wc = (wave & 1) * 64;

    fvec4 acc[4][4] = {};

    int srow = wave * 16 + (lane >> 2);
    int skk  = (lane & 3) * 8;
    const u16* ga0 = A + (size_t)(i0 + srow) * D + skk;
    const u16* ga1 = A + (size_t)(i0 + 64 + srow) * D + skk;
    const u16* gb0 = B + (size_t)(j0 + srow) * D + skk;
    const u16* gb1 = B + (size_t)(j0 + 64 + srow) * D + skk;
    u16* la0 = &As[(wave * 16) * 32];
    u16* la1 = &As[(64 + wave * 16) * 32];
    u16* lb0 = &Bs[(wave * 16) * 32];
    u16* lb1 = &Bs[(64 + wave * 16) * 32];

    int fr = lane & 15, q = lane >> 4;

    for (int k0 = 0; k0 < D; k0 += 32) {
        __syncthreads();
        gld_lds16(ga0 + k0, la0);
        gld_lds16(ga1 + k0, la1);
        gld_lds16(gb0 + k0, lb0);
        gld_lds16(gb1 + k0, lb1);
        __syncthreads();
        short8 af[4], bf[4];
#pragma unroll
        for (int t = 0; t < 4; ++t) {
            af[t] = *(const short8*)&As[(wr + t * 16 + fr) * 32 + q * 8];
            bf[t] = *(const short8*)&Bs[(wc + t * 16 + fr) * 32 + q * 8];
        }
#pragma unroll
        for (int ri = 0; ri < 4; ++ri)
#pragma unroll
            for (int ci = 0; ci < 4; ++ci)
                acc[ri][ci] = __builtin_amdgcn_mfma_f32_16x16x32_bf16(af[ri], bf[ci],
                                                                      acc[ri][ci], 0, 0, 0);
    }

    float lmax = 0.f;
#pragma unroll
    for (int ri = 0; ri < 4; ++ri) {
#pragma unroll
        for (int ci = 0; ci < 4; ++ci) {
            int j = j0 + wc + ci * 16 + fr;
#pragma unroll
            for (int r = 0; r < 4; ++r) {
                int i = i0 + wr + ri * 16 + q * 4 + r;
                float dv = acc[ri][ci][r];
                DOT[(size_t)i * N + j] = f2bf(dv);
                lmax = fmaxf(lmax, fabsf(dv));
            }
        }
    }
#pragma unroll
    for (int off = 32; off >= 1; off >>= 1) lmax = fmaxf(lmax, __shfl_xor(lmax, off));
    __shared__ float bm[4];
    if (lane == 0) bm[wave] = lmax;
    __syncthreads();
    if (tid == 0)
        blockmax[blockIdx.y * gridDim.x + blockIdx.x] =
            fmaxf(fmaxf(bm[0], bm[1]), fmaxf(bm[2], bm[3]));
}

// ---------------- consts: qs, invS, C from max|dot| ----------------
__global__ __launch_bounds__(256) void setup_consts_k(const float* __restrict__ blockmax,
                                                      float* __restrict__ consts) {
    int t = threadIdx.x;
    float m = fmaxf(fmaxf(blockmax[t], blockmax[t + 256]),
                    fmaxf(blockmax[t + 512], blockmax[t + 768]));
#pragma unroll
    for (int off = 32; off >= 1; off >>= 1) m = fmaxf(m, __shfl_xor(m, off));
    __shared__ float bm[4];
    if ((t & 63) == 0) bm[t >> 6] = m;
    __syncthreads();
    if (t == 0) {
        float maxd = fmaxf(fmaxf(bm[0], bm[1]), fmaxf(bm[2], bm[3]));
        maxd = fmaxf(maxd, 1e-6f);
        consts[0] = 127.0f / maxd;                    // qs (quant scale on dot)
        float invS = 2.0f * LOG2E * maxd / 127.0f;    // dequant step (log2 units)
        consts[1] = invS;
        consts[2] = 127.5f * invS;                    // C
    }
}

// ---------------- quantize DOT -> Q (u8), row-major ----------------
__global__ __launch_bounds__(256) void quant_k(const u16* __restrict__ DOT,
                                               const float* __restrict__ consts,
                                               u8* __restrict__ Q) {
    int idx = blockIdx.x * 256 + threadIdx.x;
    float qs = consts[0];
    ushort8 dv = *((const ushort8*)DOT + idx);
    unsigned o0 = 0, o1 = 0;
#pragma unroll
    for (int e = 0; e < 8; ++e) {
        float r = fmaf(bf2f(dv[e]), -qs, 127.5f);
        r = fminf(fmaxf(r, 0.f), 255.f);
        unsigned qq = (unsigned)(int)(r + 0.5f);
        if (e < 4) o0 |= qq << (8 * e); else o1 |= qq << (8 * (e - 4));
    }
    uivec2 o; o[0] = o0; o[1] = o1;
    *((uivec2*)Q + idx) = o;
}

// ---------------- transposing quantize: DOT -> QT (u8) ----------------
__global__ __launch_bounds__(256) void quantT_k(const u16* __restrict__ DOT,
                                                const float* __restrict__ consts,
                                                u8* __restrict__ QT) {
    __shared__ u16 tile[64][66];
    int bx = blockIdx.x * 64, by = blockIdx.y * 64;
    int t = threadIdx.x;
    int tx = t & 63, ty = t >> 6;
#pragma unroll
    for (int r = 0; r < 64; r += 4)
        tile[r + ty][tx] = DOT[(size_t)(by + r + ty) * N + bx + tx];
    __syncthreads();
    float qs = consts[0];
    int ro = t >> 2, co0 = (t & 3) << 4;
    unsigned w[4] = {0, 0, 0, 0};
#pragma unroll
    for (int k = 0; k < 16; ++k) {
        float v = bf2f(tile[co0 + k][ro]);
        float r = fminf(fmaxf(fmaf(v, -qs, 127.5f), 0.f), 255.f);
        unsigned qq = (unsigned)(int)(r + 0.5f);
        w[k >> 2] |= qq << ((k & 3) * 8);
    }
    uivec4 o; o[0] = w[0]; o[1] = w[1]; o[2] = w[2]; o[3] = w[3];
    *(uivec4*)&QT[(size_t)(bx + ro) * N + by + co0] = o;
}

// ---------------- Wg init: g=0 -> Wg = -y2c ----------------
__global__ __launch_bounds__(256) void init_wg_k(const float* __restrict__ y2c,
                                                 float* __restrict__ Wg) {
    int i = blockIdx.x * 256 + threadIdx.x;
    Wg[i] = -y2c[i];
}

// ---------------- Sinkhorn half-step on u8 Q ----------------
// tv''_j = Win_j - q_ij*invS ; LSE(tv) = LSE(tv'') + C - normR_i
// base = LA2 - C - LSE''; wout = base (next half's Win), vout = base + normR
__global__ __launch_bounds__(256, 4) void sinkhorn_half_q_k(const u8* __restrict__ Q,
                                                            const float* __restrict__ Win,
                                                            const float* __restrict__ normR,
                                                            const float* __restrict__ consts,
                                                            float* __restrict__ vout,
                                                            float* __restrict__ wout) {
    int wid  = (blockIdx.x << 2) | (threadIdx.x >> 6);  // row 0..4095
    int lane = threadIdx.x & 63;
    float invS = consts[1], C = consts[2];
    const u8* row = Q + ((size_t)wid << 12);
    float m = -1e30f, s = 0.f;
#pragma unroll
    for (int c = 0; c < 8; ++c) {
        int j = c * 512 + lane * 8;
        uivec2 qv = *(const uivec2*)(row + j);
        fvec4 w0 = *(const fvec4*)(Win + j);
        fvec4 w1 = *(const fvec4*)(Win + j + 4);
        float tv[8];
#pragma unroll
        for (int e = 0; e < 4; ++e) {
            tv[e]     = fmaf(-invS, (float)((qv[0] >> (8 * e)) & 255u), w0[e]);
            tv[4 + e] = fmaf(-invS, (float)((qv[1] >> (8 * e)) & 255u), w1[e]);
        }
        float mh = fmaxf(fmaxf(max3f(tv[0], tv[1], tv[2]), max3f(tv[3], tv[4], tv[5])),
                         max3f(tv[6], tv[7], m));
        float sh = 0.f;
#pragma unroll
        for (int e = 0; e < 8; ++e) sh += ex2(tv[e] - mh);
        s = fmaf(s, ex2(m - mh), sh);
        m = mh;
    }
#pragma unroll
    for (int off = 32; off >= 1; off >>= 1) {
        float mo = __shfl_xor(m, off);
        float so = __shfl_xor(s, off);
        float mn = fmaxf(m, mo);
        s = fmaf(s, ex2(m - mn), so * ex2(mo - mn));
        m = mn;
    }
    if (lane == 0) {
        float base = LA2 - C - (m + lg2(s));
        wout[wid] = base;
        vout[wid] = base + normR[wid];
    }
}

// ---------------- objective partials on u8 Q ----------------
// p = exp2(Wf_i + C + Wg_j - q*invS); weight = ln2*(f2_i+g2_j) + VADD
__global__ __launch_bounds__(256, 4) void ot_value_q_k(const u8* __restrict__ Q,
                                                       const float* __restrict__ Wg,
                                                       const float* __restrict__ g2,
                                                       const float* __restrict__ f2,
                                                       const float* __restrict__ Wf,
                                                       const float* __restrict__ consts,
                                                       float* __restrict__ partial) {
    int wid  = (blockIdx.x << 2) | (threadIdx.x >> 6);
    int lane = threadIdx.x & 63;
    float invS = consts[1], C = consts[2];
    const u8* row = Q + ((size_t)wid << 12);
    float fi = f2[wid];
    float eWF = Wf[wid] + C;
    float wrow = fmaf(LN2, fi, VADD);
    float local = 0.f;
#pragma unroll
    for (int c = 0; c < 8; ++c) {
        int j = c * 512 + lane * 8;
        uivec2 qv = *(const uivec2*)(row + j);
        fvec4 wg0 = *(const fvec4*)(Wg + j);
        fvec4 wg1 = *(const fvec4*)(Wg + j + 4);
        fvec4 g0 = *(const fvec4*)(g2 + j);
        fvec4 g1 = *(const fvec4*)(g2 + j + 4);
#pragma unroll
        for (int e = 0; e < 4; ++e) {
            float p0 = ex2(fmaf(-invS, (float)((qv[0] >> (8 * e)) & 255u), wg0[e]) + eWF);
            float p1 = ex2(fmaf(-invS, (float)((qv[1] >> (8 * e)) & 255u), wg1[e]) + eWF);
            local = fmaf(p0, fmaf(LN2, g0[e], wrow), local);
            local = fmaf(p1, fmaf(LN2, g1[e], wrow), local);
        }
    }
#pragma unroll
    for (int off = 32; off >= 1; off >>= 1) local += __shfl_xor(local, off);
    __shared__ float ps[4];
    if (lane == 0) ps[threadIdx.x >> 6] = local;
    __syncthreads();
    if (threadIdx.x == 0) partial[blockIdx.x] = ps[0] + ps[1] + ps[2] + ps[3];
}

__global__ __launch_bounds__(256) void value_reduce_k(const float* __restrict__ partial,
                                                      float* __restrict__ out) {
    int t = threadIdx.x;
    float s = partial[t] + partial[t + 256] + partial[t + 512] + partial[t + 768];
#pragma unroll
    for (int off = 32; off >= 1; off >>= 1) s += __shfl_xor(s, off);
    __shared__ float fs[4];
    if ((t & 63) == 0) fs[t >> 6] = s;
    __syncthreads();
    if (t == 0) out[0] = fs[0] + fs[1] + fs[2] + fs[3] + 1.0f;
}

extern "C" void kernel_launch(void* const* d_in, const int* in_sizes, int n_in,
                              void* d_out, int out_size, void* d_ws, size_t ws_size,
                              hipStream_t stream) {
    const float* src = (const float*)d_in[0];
    const float* tgt = (const float*)d_in[1];
    float* out = (float*)d_out;

    // workspace: DOT bf16 (32MB) | Qb u8 (16MB) | QTb u8 (16MB) | vectors (~128KB)
    // Xb/Yb (GEMM inputs) alias the QTb region: dead before quantT_k writes QT.
    char* ws = (char*)d_ws;
    u16* DOT = (u16*)ws;
    u8*  Qb  = (u8*)(ws + (32u << 20));
    u8*  QTb = (u8*)(ws + (48u << 20));
    u16* Xb  = (u16*)(ws + (48u << 20));
    u16* Yb  = (u16*)(ws + (52u << 20));
    float* x2c = (float*)(ws + (64u << 20));
    float* y2c = x2c + N;
    float* f   = y2c + N;
    float* g   = f + N;
    float* Wf  = g + N;
    float* Wg  = Wf + N;
    float* blockmax = Wg + N;        // 1024 floats
    float* consts   = blockmax + 1024;
    float* partial  = consts + 16;   // 1024 floats

    f32_to_bf16_k<<<N * D / (256 * 8), 256, 0, stream>>>(src, Xb);
    f32_to_bf16_k<<<N * D / (256 * 8), 256, 0, stream>>>(tgt, Yb);
    row_norms_k<<<N / 4, 256, 0, stream>>>(src, x2c);
    row_norms_k<<<N / 4, 256, 0, stream>>>(tgt, y2c);
    gemm_dot_k<<<dim3(N / 128, N / 128), 256, 0, stream>>>(Xb, Yb, DOT, blockmax);
    setup_consts_k<<<1, 256, 0, stream>>>(blockmax, consts);
    quant_k<<<N * N / (256 * 8), 256, 0, stream>>>(DOT, consts, Qb);
    quantT_k<<<dim3(N / 64, N / 64), 256, 0, stream>>>(DOT, consts, QTb);
    init_wg_k<<<N / 256, 256, 0, stream>>>(y2c, Wg);

    for (int it = 0; it < 100; ++it) {
        sinkhorn_half_q_k<<<N / 4, 256, 0, stream>>>(Qb,  Wg, x2c, consts, f, Wf);
        sinkhorn_half_q_k<<<N / 4, 256, 0, stream>>>(QTb, Wf, y2c, consts, g, Wg);
    }

    ot_value_q_k<<<N / 4, 256, 0, stream>>>(Qb, Wg, g, f, Wf, consts, partial);
    value_reduce_k<<<1, 256, 0, stream>>>(partial, out);
}